// Round 2
// baseline (3211.103 us; speedup 1.0000x reference)
//
#include <hip/hip_runtime.h>
#include <hip/hip_bf16.h>
#include <cstdint>

typedef __hip_bfloat16 bf16;
#define DEVI __device__ __forceinline__

DEVI float b2f(bf16 v){ return __bfloat162float(v); }
DEVI bf16 f2b(float v){ return __float2bfloat16(v); }
DEVI float lrelu(float x, float s){ return x > 0.f ? x : x * s; }

// dtype-adaptive accessors: f==1 -> bf16 data, f==0 -> float32 data
DEVI float ldf(const void* p, size_t i, int f){
  return f ? b2f(((const bf16*)p)[i]) : ((const float*)p)[i];
}
DEVI void stf(void* p, size_t i, int f, float v){
  if(f) ((bf16*)p)[i] = f2b(v); else ((float*)p)[i] = v;
}

DEVI float wave_sum(float v){
#pragma unroll
  for(int o = 32; o > 0; o >>= 1) v += __shfl_xor(v, o, 64);
  return v;
}

// ---- dtype detector ---------------------------------------------------------
__global__ void k_detect(const uint32_t* __restrict__ xf, int* flag){
  if(threadIdx.x == 0 && blockIdx.x == 0){
    int cnt = 0;
    for(int i = 0; i < 256; i++){
      uint32_t e = (xf[i] >> 7) & 0xFF;
      if(e >= 100 && e <= 140) cnt++;
    }
    *flag = (cnt > 180) ? 1 : 0;
  }
}

// ---- encoder ----------------------------------------------------------------
__global__ __launch_bounds__(256) void k_encoder(
    const void* __restrict__ xf, const int* __restrict__ ids,
    const void* __restrict__ emb, const void* __restrict__ win,
    const void* __restrict__ bin, float* __restrict__ x,
    const int* __restrict__ flagp, int N)
{
  __shared__ float W[128*64];
  __shared__ float B[64];
  __shared__ float XR[4][128];
  const int t = threadIdx.x;
  const int f = *flagp;
  for(int i = t; i < 128*64; i += 256) W[i] = ldf(win, i, f);
  if(t < 64) B[t] = ldf(bin, t, f);
  __syncthreads();
  const int w = t >> 6, lane = t & 63;
  for(int base = blockIdx.x*4; base < N; base += gridDim.x*4){
    const int node = base + w;
    if(node < N){
      for(int k = lane; k < 128; k += 64){
        float v;
        if(k < 124) v = ldf(xf, (size_t)node*124 + k, f);
        else        v = ldf(emb, (size_t)ids[node]*4 + (k-124), f);
        XR[w][k] = v;
      }
      float acc = B[lane];
#pragma unroll 8
      for(int k = 0; k < 128; k++) acc = fmaf(XR[w][k], W[k*64+lane], acc);
      x[(size_t)node*64 + lane] = lrelu(acc, 0.01f);
    }
  }
}

// ---- per-layer linear -------------------------------------------------------
__global__ __launch_bounds__(256) void k_linear(
    const float* __restrict__ x, const void* __restrict__ lw,
    const void* __restrict__ lb, float* __restrict__ g,
    const int* __restrict__ flagp, int layer, int N)
{
  __shared__ float W[64*64];
  __shared__ float B[64];
  __shared__ float XR[4][64];
  const int t = threadIdx.x;
  const int f = *flagp;
  const size_t wofs = (size_t)layer*64*64, bofs = (size_t)layer*64;
  for(int i = t; i < 64*64; i += 256) W[i] = ldf(lw, wofs + i, f);
  if(t < 64) B[t] = ldf(lb, bofs + t, f);
  __syncthreads();
  const int w = t >> 6, lane = t & 63;
  for(int base = blockIdx.x*4; base < N; base += gridDim.x*4){
    const int node = base + w;
    if(node < N){
      XR[w][lane] = x[(size_t)node*64 + lane];
      float acc = B[lane];
#pragma unroll 8
      for(int k = 0; k < 64; k++) acc = fmaf(XR[w][k], W[k*64+lane], acc);
      g[(size_t)node*64 + lane] = acc;
    }
  }
}

// ---- CSR build --------------------------------------------------------------
__global__ void k_deg_init(int* deg, int N){
  int i = blockIdx.x*blockDim.x + threadIdx.x;
  if(i < N) deg[i] = 1;  // self-loop
}
__global__ void k_deg_count(const int* __restrict__ dst, int* deg, int E){
  int j = blockIdx.x*blockDim.x + threadIdx.x;
  if(j < E) atomicAdd(&deg[dst[j]], 1);
}
__global__ __launch_bounds__(256) void k_scan_partial(const int* __restrict__ deg, int* partial, int N){
  __shared__ int red[256];
  const int c = blockIdx.x, base = c*1024, t = threadIdx.x;
  int s = 0;
  for(int i = t; i < 1024; i += 256){ int idx = base+i; s += (idx < N) ? deg[idx] : 0; }
  red[t] = s; __syncthreads();
  for(int o = 128; o > 0; o >>= 1){ if(t < o) red[t] += red[t+o]; __syncthreads(); }
  if(t == 0) partial[c] = red[0];
}
__global__ void k_scan_top(int* partial, int nchunks){
  if(threadIdx.x == 0 && blockIdx.x == 0){
    int run = 0;
    for(int i = 0; i < nchunks; i++){ int v = partial[i]; partial[i] = run; run += v; }
  }
}
__global__ __launch_bounds__(256) void k_scan_final(
    const int* __restrict__ deg, const int* __restrict__ partial,
    int* __restrict__ off, int* __restrict__ cur, int N)
{
  __shared__ int vals[1024];
  __shared__ int tsum[256];
  const int c = blockIdx.x, base = c*1024, t = threadIdx.x;
  for(int i = t; i < 1024; i += 256){ int idx = base+i; vals[i] = (idx < N) ? deg[idx] : 0; }
  __syncthreads();
  int a0 = vals[t*4], a1 = vals[t*4+1], a2 = vals[t*4+2], a3 = vals[t*4+3];
  int s = a0+a1+a2+a3;
  tsum[t] = s; __syncthreads();
  for(int o = 1; o < 256; o <<= 1){
    int v = (t >= o) ? tsum[t-o] : 0;
    __syncthreads();
    tsum[t] += v;
    __syncthreads();
  }
  int excl = tsum[t] - s + partial[c];
  int o0 = excl, o1 = o0+a0, o2 = o1+a1, o3 = o2+a2;
  int idx = base + t*4;
  if(idx   < N){ off[idx]   = o0; cur[idx]   = o0; }
  if(idx+1 < N){ off[idx+1] = o1; cur[idx+1] = o1; }
  if(idx+2 < N){ off[idx+2] = o2; cur[idx+2] = o2; }
  if(idx+3 < N){ off[idx+3] = o3; cur[idx+3] = o3; }
}
__global__ void k_scatter(const int* __restrict__ src, const int* __restrict__ dst,
                          int* cur, int* __restrict__ ceid, int* __restrict__ csrc,
                          int E, int N){
  int j = blockIdx.x*blockDim.x + threadIdx.x;
  int T = E + N;
  if(j >= T) return;
  int s, d;
  if(j < E){ s = src[j]; d = dst[j]; } else { s = j - E; d = s; }
  int p = atomicAdd(&cur[d], 1);
  ceid[p] = j; csrc[p] = s;
}

// ---- fused GATv2 + GraphNorm stats ------------------------------------------
__global__ __launch_bounds__(256) void k_gat(
    const float* __restrict__ g, const int* __restrict__ off,
    const int* __restrict__ deg, const int* __restrict__ ceid,
    const int* __restrict__ csrc, const void* __restrict__ att,
    const void* __restrict__ convb, float* __restrict__ xout,
    void* __restrict__ out, size_t alpha_base, float* __restrict__ stats,
    const int* __restrict__ flagp, int layer, int N)
{
  __shared__ float sv[4][64], sv2[4][64];
  const int t = threadIdx.x, w = t >> 6, lane = t & 63;
  const int f = *flagp;
  const size_t pofs = (size_t)layer*64;
  const int node = blockIdx.x*4 + w;
  const bool act = node < N;
  const float att_c = ldf(att, pofs + lane, f);
  float v = 0.f;
  if(act){
    const float gd = g[(size_t)node*64 + lane];
    const int o = off[node];
    const int d = deg[node];
    float m = -1e30f, sp = 0.f, acc = 0.f, ereg = 0.f;
    for(int j = 0; j < d; j++){
      const int s = csrc[o+j];
      const float gs = g[(size_t)s*64 + lane];
      const float e = wave_sum(lrelu(gs + gd, 0.2f) * att_c);
      if(lane == j) ereg = e;               // register e-cache (j<64)
      const float mn = fmaxf(m, e);
      const float sc = __expf(m - mn);      // first iter: exp(-inf)=0
      const float ww = __expf(e - mn);
      sp  = sp*sc  + ww;
      acc = acc*sc + ww*gs;
      m = mn;
    }
    const float inv = 1.f / sp;
    const int dc = d < 64 ? d : 64;
    if(lane < dc)
      stf(out, alpha_base + (size_t)ceid[o+lane], f, __expf(ereg - m) * inv);
    for(int j = 64; j < d; j++){            // rare tail (deg>64)
      const int s = csrc[o+j];
      const float gs = g[(size_t)s*64 + lane];
      const float e = wave_sum(lrelu(gs + gd, 0.2f) * att_c);
      if(lane == 0) stf(out, alpha_base + (size_t)ceid[o+j], f, __expf(e - m) * inv);
    }
    v = acc * inv + ldf(convb, pofs + lane, f);
    xout[(size_t)node*64 + lane] = v;
  }
  sv[w][lane] = v; sv2[w][lane] = v*v;
  __syncthreads();
  if(w == 0){
    float a = sv[0][lane]+sv[1][lane]+sv[2][lane]+sv[3][lane];
    float b = sv2[0][lane]+sv2[1][lane]+sv2[2][lane]+sv2[3][lane];
    atomicAdd(&stats[lane],    a);
    atomicAdd(&stats[64+lane], b);
  }
}

// ---- GraphNorm apply --------------------------------------------------------
__global__ void k_zero_stats(float* stats){ stats[threadIdx.x] = 0.f; }

__global__ __launch_bounds__(256) void k_gn_apply(
    float* __restrict__ x, const float* __restrict__ stats,
    const void* __restrict__ gw, const void* __restrict__ gb,
    const void* __restrict__ gms, void* __restrict__ out,
    size_t x_base, size_t h_base, const int* __restrict__ flagp,
    int N, int layer, float invN)
{
  const int f = *flagp;
  const int lane = threadIdx.x & 63;
  const size_t pofs = (size_t)layer*64;
  const float mean = stats[lane] * invN;
  const float ex2  = stats[64+lane] * invN;
  const float c    = mean * ldf(gms, pofs + lane, f);
  const float var  = ex2 - 2.f*c*mean + c*c;   // E[(x-c)^2]
  const float a    = ldf(gw, pofs + lane, f) / sqrtf(var + 1e-5f);
  const float bb   = ldf(gb, pofs + lane, f);
  const size_t total = (size_t)N * 64;
  for(size_t idx = (size_t)blockIdx.x*256 + threadIdx.x; idx < total;
      idx += (size_t)gridDim.x*256){
    float v = (x[idx] - c) * a + bb;
    v = lrelu(v, 0.01f);
    x[idx] = v;
    float hv = 0.5f*v + (layer == 0 ? 0.f : ldf(out, h_base + idx, f));
    stf(out, h_base + idx, f, hv);
    if(layer == 3) stf(out, x_base + idx, f, v);
  }
}

// ---- host launch ------------------------------------------------------------
extern "C" void kernel_launch(void* const* d_in, const int* in_sizes, int n_in,
                              void* d_out, int out_size, void* d_ws, size_t ws_size,
                              hipStream_t stream) {
  const void* xf   = d_in[0];
  const int*  ids  = (const int*)d_in[1];
  const int*  eidx = (const int*)d_in[2];
  const void* emb  = d_in[3];
  const void* win  = d_in[4];
  const void* bin  = d_in[5];
  const void* lw   = d_in[6];
  const void* lb   = d_in[7];
  const void* att  = d_in[8];
  const void* cb   = d_in[9];
  const void* gw   = d_in[10];
  const void* gb   = d_in[11];
  const void* gms  = d_in[12];

  const int N = in_sizes[1];
  const int E = in_sizes[2] / 2;
  const int T = E + N;
  const int* srcp = eidx;
  const int* dstp = eidx + E;

  // workspace carve (~66 MB)
  char* p = (char*)d_ws;
  float* x  = (float*)p; p += (size_t)N*64*4;
  float* g  = (float*)p; p += (size_t)N*64*4;
  int* deg  = (int*)p;   p += ((size_t)N*4 + 63) & ~63ull;
  int* off  = (int*)p;   p += ((size_t)N*4 + 63) & ~63ull;
  int* cur  = (int*)p;   p += ((size_t)N*4 + 63) & ~63ull;
  int* ceid = (int*)p;   p += ((size_t)T*4 + 63) & ~63ull;
  int* csrc = (int*)p;   p += ((size_t)T*4 + 63) & ~63ull;
  int* partial = (int*)p; p += 4096;
  float* stats = (float*)p; p += 512;
  int* flag = (int*)p;    p += 64;

  const size_t x_base = 0;
  const size_t h_base = (size_t)N*64;
  const size_t a_base = (size_t)2*N*64;

  k_detect<<<1, 64, 0, stream>>>((const uint32_t*)xf, flag);
  k_encoder<<<2048, 256, 0, stream>>>(xf, ids, emb, win, bin, x, flag, N);

  k_deg_init <<<(N+255)/256, 256, 0, stream>>>(deg, N);
  k_deg_count<<<(E+255)/256, 256, 0, stream>>>(dstp, deg, E);
  const int nchunks = (N + 1023) / 1024;
  k_scan_partial<<<nchunks, 256, 0, stream>>>(deg, partial, N);
  k_scan_top    <<<1, 1, 0, stream>>>(partial, nchunks);
  k_scan_final  <<<nchunks, 256, 0, stream>>>(deg, partial, off, cur, N);
  k_scatter     <<<(T+255)/256, 256, 0, stream>>>(srcp, dstp, cur, ceid, csrc, E, N);

  for(int l = 0; l < 4; l++){
    k_zero_stats<<<1, 128, 0, stream>>>(stats);
    k_linear<<<2048, 256, 0, stream>>>(x, lw, lb, g, flag, l, N);
    k_gat<<<(N+3)/4, 256, 0, stream>>>(g, off, deg, ceid, csrc, att, cb, x,
                                       d_out, a_base + (size_t)l*T, stats, flag, l, N);
    k_gn_apply<<<1024, 256, 0, stream>>>(x, stats, gw, gb, gms, d_out,
                                         x_base, h_base, flag, N, l, 1.0f/(float)N);
  }
}

// Round 3
// 3169.665 us; speedup vs baseline: 1.0131x; 1.0131x over previous
//
#include <hip/hip_runtime.h>
#include <hip/hip_bf16.h>
#include <cstdint>

typedef __hip_bfloat16 bf16;
#define DEVI __device__ __forceinline__

DEVI float b2f(bf16 v){ return __bfloat162float(v); }
DEVI bf16 f2b(float v){ return __float2bfloat16(v); }
DEVI float lrelu(float x, float s){ return x > 0.f ? x : x * s; }

// dtype-adaptive accessors: f==1 -> bf16 data, f==0 -> float32 data
DEVI float ldf(const void* p, size_t i, int f){
  return f ? b2f(((const bf16*)p)[i]) : ((const float*)p)[i];
}
DEVI void stf(void* p, size_t i, int f, float v){
  if(f) ((bf16*)p)[i] = f2b(v); else ((float*)p)[i] = v;
}

DEVI float wave_sum(float v){
#pragma unroll
  for(int o = 32; o > 0; o >>= 1) v += __shfl_xor(v, o, 64);
  return v;
}
// sum within 16-lane quarter (4 quarters reduce simultaneously)
DEVI float qsum(float v){
  v += __shfl_xor(v, 1, 64);
  v += __shfl_xor(v, 2, 64);
  v += __shfl_xor(v, 4, 64);
  v += __shfl_xor(v, 8, 64);
  return v;
}

// ---- dtype detector ---------------------------------------------------------
__global__ void k_detect(const uint32_t* __restrict__ xf, int* flag){
  const int lane = threadIdx.x & 63;
  float cnt = 0.f;
  for(int i = lane; i < 256; i += 64){
    uint32_t e = (xf[i] >> 7) & 0xFF;
    if(e >= 100 && e <= 140) cnt += 1.f;
  }
  cnt = wave_sum(cnt);
  if(lane == 0 && blockIdx.x == 0) *flag = (cnt > 180.f) ? 1 : 0;
}

// ---- encoder ----------------------------------------------------------------
__global__ __launch_bounds__(256) void k_encoder(
    const void* __restrict__ xf, const int* __restrict__ ids,
    const void* __restrict__ emb, const void* __restrict__ win,
    const void* __restrict__ bin, float* __restrict__ x,
    const int* __restrict__ flagp, int N)
{
  __shared__ float W[128*64];
  __shared__ float B[64];
  __shared__ float XR[4][128];
  const int t = threadIdx.x;
  const int f = *flagp;
  for(int i = t; i < 128*64; i += 256) W[i] = ldf(win, i, f);
  if(t < 64) B[t] = ldf(bin, t, f);
  __syncthreads();
  const int w = t >> 6, lane = t & 63;
  for(int base = blockIdx.x*4; base < N; base += gridDim.x*4){
    const int node = base + w;
    if(node < N){
      for(int k = lane; k < 128; k += 64){
        float v;
        if(k < 124) v = ldf(xf, (size_t)node*124 + k, f);
        else        v = ldf(emb, (size_t)ids[node]*4 + (k-124), f);
        XR[w][k] = v;
      }
      float acc = B[lane];
#pragma unroll 8
      for(int k = 0; k < 128; k++) acc = fmaf(XR[w][k], W[k*64+lane], acc);
      x[(size_t)node*64 + lane] = lrelu(acc, 0.01f);
    }
  }
}

// ---- per-layer linear -------------------------------------------------------
__global__ __launch_bounds__(256) void k_linear(
    const float* __restrict__ x, const void* __restrict__ lw,
    const void* __restrict__ lb, float* __restrict__ g,
    const int* __restrict__ flagp, int layer, int N)
{
  __shared__ float W[64*64];
  __shared__ float B[64];
  __shared__ float XR[4][64];
  const int t = threadIdx.x;
  const int f = *flagp;
  const size_t wofs = (size_t)layer*64*64, bofs = (size_t)layer*64;
  for(int i = t; i < 64*64; i += 256) W[i] = ldf(lw, wofs + i, f);
  if(t < 64) B[t] = ldf(lb, bofs + t, f);
  __syncthreads();
  const int w = t >> 6, lane = t & 63;
  for(int base = blockIdx.x*4; base < N; base += gridDim.x*4){
    const int node = base + w;
    if(node < N){
      XR[w][lane] = x[(size_t)node*64 + lane];
      float acc = B[lane];
#pragma unroll 8
      for(int k = 0; k < 64; k++) acc = fmaf(XR[w][k], W[k*64+lane], acc);
      g[(size_t)node*64 + lane] = acc;
    }
  }
}

// ---- CSR build --------------------------------------------------------------
__global__ void k_deg_init(int* deg, int N){
  int i = blockIdx.x*blockDim.x + threadIdx.x;
  if(i < N) deg[i] = 1;  // self-loop
}
__global__ void k_deg_count(const int* __restrict__ dst, int* deg, int E){
  int j = blockIdx.x*blockDim.x + threadIdx.x;
  if(j < E) atomicAdd(&deg[dst[j]], 1);
}
__global__ __launch_bounds__(256) void k_scan_partial(const int* __restrict__ deg, int* partial, int N){
  __shared__ int red[256];
  const int c = blockIdx.x, base = c*1024, t = threadIdx.x;
  int s = 0;
  for(int i = t; i < 1024; i += 256){ int idx = base+i; s += (idx < N) ? deg[idx] : 0; }
  red[t] = s; __syncthreads();
  for(int o = 128; o > 0; o >>= 1){ if(t < o) red[t] += red[t+o]; __syncthreads(); }
  if(t == 0) partial[c] = red[0];
}
__global__ void k_scan_top(int* partial, int nchunks){
  if(threadIdx.x == 0 && blockIdx.x == 0){
    int run = 0;
    for(int i = 0; i < nchunks; i++){ int v = partial[i]; partial[i] = run; run += v; }
  }
}
__global__ __launch_bounds__(256) void k_scan_final(
    const int* __restrict__ deg, const int* __restrict__ partial,
    int* __restrict__ off, int* __restrict__ cur, int N)
{
  __shared__ int vals[1024];
  __shared__ int tsum[256];
  const int c = blockIdx.x, base = c*1024, t = threadIdx.x;
  for(int i = t; i < 1024; i += 256){ int idx = base+i; vals[i] = (idx < N) ? deg[idx] : 0; }
  __syncthreads();
  int a0 = vals[t*4], a1 = vals[t*4+1], a2 = vals[t*4+2], a3 = vals[t*4+3];
  int s = a0+a1+a2+a3;
  tsum[t] = s; __syncthreads();
  for(int o = 1; o < 256; o <<= 1){
    int v = (t >= o) ? tsum[t-o] : 0;
    __syncthreads();
    tsum[t] += v;
    __syncthreads();
  }
  int excl = tsum[t] - s + partial[c];
  int o0 = excl, o1 = o0+a0, o2 = o1+a1, o3 = o2+a2;
  int idx = base + t*4;
  if(idx   < N){ off[idx]   = o0; cur[idx]   = o0; }
  if(idx+1 < N){ off[idx+1] = o1; cur[idx+1] = o1; }
  if(idx+2 < N){ off[idx+2] = o2; cur[idx+2] = o2; }
  if(idx+3 < N){ off[idx+3] = o3; cur[idx+3] = o3; }
}
__global__ void k_scatter(const int* __restrict__ src, const int* __restrict__ dst,
                          int* cur, int* __restrict__ ceid, int* __restrict__ csrc,
                          int E, int N){
  int j = blockIdx.x*blockDim.x + threadIdx.x;
  int T = E + N;
  if(j >= T) return;
  int s, d;
  if(j < E){ s = src[j]; d = dst[j]; } else { s = j - E; d = s; }
  int p = atomicAdd(&cur[d], 1);
  ceid[p] = j; csrc[p] = s;
}

// ---- fused GATv2 (quarter-wave, 4 edges in flight) + GraphNorm stats --------
__global__ __launch_bounds__(256) void k_gat(
    const float* __restrict__ g, const int* __restrict__ off,
    const int* __restrict__ deg, const int* __restrict__ ceid,
    const int* __restrict__ csrc, const void* __restrict__ att,
    const void* __restrict__ convb, float* __restrict__ xout,
    void* __restrict__ out, size_t alpha_base, float* __restrict__ stats,
    const int* __restrict__ flagp, int layer, int N)
{
  __shared__ float sv[4][64], sv2[4][64];
  const int t = threadIdx.x, w = t >> 6, lane = t & 63;
  const int q = lane >> 4, L = lane & 15;
  const int f = *flagp;
  const size_t pofs = (size_t)layer*64;
  const int node = blockIdx.x*4 + w;
  const bool act = node < N;
  const int nc = act ? node : (N-1);

  // per-lane channel block c = 4L..4L+3 (same in every quarter)
  float4 attv, cbv;
  attv.x = ldf(att, pofs + 4*L+0, f); attv.y = ldf(att, pofs + 4*L+1, f);
  attv.z = ldf(att, pofs + 4*L+2, f); attv.w = ldf(att, pofs + 4*L+3, f);
  cbv.x = ldf(convb, pofs + 4*L+0, f); cbv.y = ldf(convb, pofs + 4*L+1, f);
  cbv.z = ldf(convb, pofs + 4*L+2, f); cbv.w = ldf(convb, pofs + 4*L+3, f);

  const float4 gd = *(const float4*)(g + (size_t)nc*64 + 4*L);
  const int o = off[nc];
  const int d = act ? deg[nc] : 0;
  // preload up to 64 source ids, coalesced; broadcast later via shfl
  const int sreg = csrc[o + (lane < d ? lane : 0)];

  float m = -1e30f, sp = 0.f, ereg = -1e30f;
  float4 acc = {0.f, 0.f, 0.f, 0.f};
  const int nit = (d + 3) >> 2;
  for(int i = 0; i < nit; i++){
    const int j = i*4 + q;                 // this quarter's edge
    const bool have = j < d;
    int s;
    if(i < 16) s = __shfl(sreg, j, 64);
    else       s = csrc[o + (have ? j : 0)];
    const float4 gs = *(const float4*)(g + (size_t)s*64 + 4*L);
    float pe = lrelu(gs.x+gd.x, 0.2f)*attv.x + lrelu(gs.y+gd.y, 0.2f)*attv.y
             + lrelu(gs.z+gd.z, 0.2f)*attv.z + lrelu(gs.w+gd.w, 0.2f)*attv.w;
    float e = qsum(pe);
    if(!have) e = -1e30f;
    ereg = (L == i) ? e : ereg;            // lane q*16+i caches e of edge 4i+q
    const float mn = fmaxf(m, e);
    const float sc = __expf(m - mn);       // first valid iter: exp(-inf)=0
    const float wt = __expf(e - mn);
    sp    = sp*sc    + wt;
    acc.x = acc.x*sc + wt*gs.x;
    acc.y = acc.y*sc + wt*gs.y;
    acc.z = acc.z*sc + wt*gs.z;
    acc.w = acc.w*sc + wt*gs.w;
    m = mn;
  }
  // merge the 4 per-quarter online-softmax states (xor 16, then 32)
#pragma unroll
  for(int ofs = 16; ofs <= 32; ofs <<= 1){
    const float m2  = __shfl_xor(m,  ofs, 64);
    const float sp2 = __shfl_xor(sp, ofs, 64);
    float4 a2;
    a2.x = __shfl_xor(acc.x, ofs, 64); a2.y = __shfl_xor(acc.y, ofs, 64);
    a2.z = __shfl_xor(acc.z, ofs, 64); a2.w = __shfl_xor(acc.w, ofs, 64);
    const float mn = fmaxf(m, m2);
    const float sA = __expf(m - mn), sB = __expf(m2 - mn);
    sp    = sp*sA    + sp2*sB;
    acc.x = acc.x*sA + a2.x*sB;
    acc.y = acc.y*sA + a2.y*sB;
    acc.z = acc.z*sA + a2.z*sB;
    acc.w = acc.w*sA + a2.w*sB;
    m = mn;
  }
  const float inv = 1.f / sp;

  if(act){
    // alpha for edges 0..min(d,64): lane q*16+L holds e of edge 4L+q
    const int j = 4*L + q;
    if(j < d && j < 64)
      stf(out, alpha_base + (size_t)ceid[o+j], f, __expf(ereg - m) * inv);
    // rare tail d>64: recompute e
    for(int i = 16; i < nit; i++){
      const int j2 = i*4 + q;
      const bool have = j2 < d;
      const int s = csrc[o + (have ? j2 : 0)];
      const float4 gs = *(const float4*)(g + (size_t)s*64 + 4*L);
      float pe = lrelu(gs.x+gd.x, 0.2f)*attv.x + lrelu(gs.y+gd.y, 0.2f)*attv.y
               + lrelu(gs.z+gd.z, 0.2f)*attv.z + lrelu(gs.w+gd.w, 0.2f)*attv.w;
      float e = qsum(pe);
      if(have && L == 0)
        stf(out, alpha_base + (size_t)ceid[o+j2], f, __expf(e - m) * inv);
    }
  }
  float4 v4 = {0.f, 0.f, 0.f, 0.f};
  if(act){
    v4.x = acc.x*inv + cbv.x; v4.y = acc.y*inv + cbv.y;
    v4.z = acc.z*inv + cbv.z; v4.w = acc.w*inv + cbv.w;
    if(q == 0) *(float4*)(xout + (size_t)node*64 + 4*L) = v4;
  }
  if(q == 0){
    sv [w][4*L+0] = v4.x;      sv [w][4*L+1] = v4.y;
    sv [w][4*L+2] = v4.z;      sv [w][4*L+3] = v4.w;
    sv2[w][4*L+0] = v4.x*v4.x; sv2[w][4*L+1] = v4.y*v4.y;
    sv2[w][4*L+2] = v4.z*v4.z; sv2[w][4*L+3] = v4.w*v4.w;
  }
  __syncthreads();
  if(w == 0){
    float a = sv[0][lane]+sv[1][lane]+sv[2][lane]+sv[3][lane];
    float b = sv2[0][lane]+sv2[1][lane]+sv2[2][lane]+sv2[3][lane];
    atomicAdd(&stats[lane],    a);
    atomicAdd(&stats[64+lane], b);
  }
}

// ---- GraphNorm apply --------------------------------------------------------
__global__ void k_zero_stats(float* stats){ stats[threadIdx.x] = 0.f; }

__global__ __launch_bounds__(256) void k_gn_apply(
    float* __restrict__ x, const float* __restrict__ stats,
    const void* __restrict__ gw, const void* __restrict__ gb,
    const void* __restrict__ gms, void* __restrict__ out,
    size_t x_base, size_t h_base, const int* __restrict__ flagp,
    int N, int layer, float invN)
{
  const int f = *flagp;
  const int lane = threadIdx.x & 63;
  const size_t pofs = (size_t)layer*64;
  const float mean = stats[lane] * invN;
  const float ex2  = stats[64+lane] * invN;
  const float c    = mean * ldf(gms, pofs + lane, f);
  const float var  = ex2 - 2.f*c*mean + c*c;   // E[(x-c)^2]
  const float a    = ldf(gw, pofs + lane, f) / sqrtf(var + 1e-5f);
  const float bb   = ldf(gb, pofs + lane, f);
  const size_t total = (size_t)N * 64;
  for(size_t idx = (size_t)blockIdx.x*256 + threadIdx.x; idx < total;
      idx += (size_t)gridDim.x*256){
    float v = (x[idx] - c) * a + bb;
    v = lrelu(v, 0.01f);
    x[idx] = v;
    float hv = 0.5f*v + (layer == 0 ? 0.f : ldf(out, h_base + idx, f));
    stf(out, h_base + idx, f, hv);
    if(layer == 3) stf(out, x_base + idx, f, v);
  }
}

// ---- host launch ------------------------------------------------------------
extern "C" void kernel_launch(void* const* d_in, const int* in_sizes, int n_in,
                              void* d_out, int out_size, void* d_ws, size_t ws_size,
                              hipStream_t stream) {
  const void* xf   = d_in[0];
  const int*  ids  = (const int*)d_in[1];
  const int*  eidx = (const int*)d_in[2];
  const void* emb  = d_in[3];
  const void* win  = d_in[4];
  const void* bin  = d_in[5];
  const void* lw   = d_in[6];
  const void* lb   = d_in[7];
  const void* att  = d_in[8];
  const void* cb   = d_in[9];
  const void* gw   = d_in[10];
  const void* gb   = d_in[11];
  const void* gms  = d_in[12];

  const int N = in_sizes[1];
  const int E = in_sizes[2] / 2;
  const int T = E + N;
  const int* srcp = eidx;
  const int* dstp = eidx + E;

  // workspace carve (~66 MB)
  char* p = (char*)d_ws;
  float* x  = (float*)p; p += (size_t)N*64*4;
  float* g  = (float*)p; p += (size_t)N*64*4;
  int* deg  = (int*)p;   p += ((size_t)N*4 + 63) & ~63ull;
  int* off  = (int*)p;   p += ((size_t)N*4 + 63) & ~63ull;
  int* cur  = (int*)p;   p += ((size_t)N*4 + 63) & ~63ull;
  int* ceid = (int*)p;   p += ((size_t)T*4 + 63) & ~63ull;
  int* csrc = (int*)p;   p += ((size_t)T*4 + 63) & ~63ull;
  int* partial = (int*)p; p += 4096;
  float* stats = (float*)p; p += 512;
  int* flag = (int*)p;    p += 64;

  const size_t x_base = 0;
  const size_t h_base = (size_t)N*64;
  const size_t a_base = (size_t)2*N*64;

  k_detect<<<1, 64, 0, stream>>>((const uint32_t*)xf, flag);
  k_encoder<<<2048, 256, 0, stream>>>(xf, ids, emb, win, bin, x, flag, N);

  k_deg_init <<<(N+255)/256, 256, 0, stream>>>(deg, N);
  k_deg_count<<<(E+255)/256, 256, 0, stream>>>(dstp, deg, E);
  const int nchunks = (N + 1023) / 1024;
  k_scan_partial<<<nchunks, 256, 0, stream>>>(deg, partial, N);
  k_scan_top    <<<1, 1, 0, stream>>>(partial, nchunks);
  k_scan_final  <<<nchunks, 256, 0, stream>>>(deg, partial, off, cur, N);
  k_scatter     <<<(T+255)/256, 256, 0, stream>>>(srcp, dstp, cur, ceid, csrc, E, N);

  for(int l = 0; l < 4; l++){
    k_zero_stats<<<1, 128, 0, stream>>>(stats);
    k_linear<<<2048, 256, 0, stream>>>(x, lw, lb, g, flag, l, N);
    k_gat<<<(N+3)/4, 256, 0, stream>>>(g, off, deg, ceid, csrc, att, cb, x,
                                       d_out, a_base + (size_t)l*T, stats, flag, l, N);
    k_gn_apply<<<1024, 256, 0, stream>>>(x, stats, gw, gb, gms, d_out,
                                         x_base, h_base, flag, N, l, 1.0f/(float)N);
  }
}